// Round 2
// baseline (2673.822 us; speedup 1.0000x reference)
//
#include <hip/hip_runtime.h>
#include <math.h>

#define BSZ   384
#define BM1   383
#define DIM   256
#define NZTOT 768
#define NBLK  128
#define RPB   3
#define TPB   384
#define NITER 100
#define RING  4

// ---- ws layout (float offsets) ----
#define OFF_Z    0          // 768*256 = 196608
#define OFF_NRM  196608     // 768
#define OFF_K    197376     // 384*768 = 294912
#define OFF_A    492288     // 384*383 = 147072 (final alpha)
#define OFF_NUM  639360     // NITER floats (pad 128)
#define OFF_DEN  639488     // NITER floats (pad 128)
#define OFF_ARR  639616     // NITER ints  (pad 128)
#define OFF_LOSS 639744     // 2 doubles (byte 2558976, 8B aligned)
// total ~2.56 MB

__global__ void init_kernel(float* num, float* den, int* arr, double* lossAcc) {
    int t = threadIdx.x;
    if (t < NITER) { num[t] = 0.f; den[t] = 0.f; arr[t] = 0; }
    if (t < 2) lossAcc[t] = 0.0;
}

__global__ void __launch_bounds__(64)
norm_kernel(const float* __restrict__ xis, const float* __restrict__ xjs,
            float* __restrict__ Z, float* __restrict__ nrm2) {
    const int row  = blockIdx.x;     // 0..767
    const int lane = threadIdx.x;    // 0..63
    const float* src = (row < BSZ) ? (xis + (size_t)row * DIM)
                                   : (xjs + (size_t)(row - BSZ) * DIM);
    float4 x = reinterpret_cast<const float4*>(src)[lane];
    float s = x.x*x.x + x.y*x.y + x.z*x.z + x.w*x.w;
    for (int m = 32; m; m >>= 1) s += __shfl_xor(s, m, 64);
    float nrm = sqrtf(s);
    float4 z;
    z.x = x.x / nrm; z.y = x.y / nrm; z.z = x.z / nrm; z.w = x.w / nrm;
    reinterpret_cast<float4*>(Z + (size_t)row * DIM)[lane] = z;
    float s2 = z.x*z.x + z.y*z.y + z.z*z.z + z.w*z.w;
    for (int m = 32; m; m >>= 1) s2 += __shfl_xor(s2, m, 64);
    if (lane == 0) nrm2[row] = s2;
}

__global__ void __launch_bounds__(256)
k_kernel(const float* __restrict__ Z, const float* __restrict__ nrm2,
         float* __restrict__ Km) {
    const int i = blockIdx.x;                        // 0..383
    const int j = blockIdx.y * 256 + threadIdx.x;    // 0..767
    __shared__ float zi[DIM];
    zi[threadIdx.x] = Z[(size_t)i * DIM + threadIdx.x];
    __syncthreads();
    const float4* zr = reinterpret_cast<const float4*>(Z + (size_t)j * DIM);
    float acc = 0.f;
    #pragma unroll 8
    for (int k = 0; k < DIM/4; ++k) {
        float4 v = zr[k];
        acc = fmaf(zi[4*k+0], v.x, acc);
        acc = fmaf(zi[4*k+1], v.y, acc);
        acc = fmaf(zi[4*k+2], v.z, acc);
        acc = fmaf(zi[4*k+3], v.w, acc);
    }
    float sq = nrm2[i] + nrm2[j] - 2.f * acc;
    sq = fmaxf(sq, 0.f);
    Km[(size_t)i * NZTOT + j] = expf(-0.1f * sq);
}

__global__ void __launch_bounds__(TPB, 1)
pgd_kernel(const float* __restrict__ Km, const float* __restrict__ alpha_init,
           float* __restrict__ afin, float* num, float* den, int* arr) {
    const int g    = blockIdx.x;     // 0..127
    const int tid  = threadIdx.x;    // 0..383
    const int lane = tid & 63;
    const int wv   = tid >> 6;       // 0..5

    __shared__ float zpack[BSZ][4];          // z for 3 rows, packed per J (pad word 3)
    __shared__ float wpart[2][RPB][BSZ];     // per-half partial matvec
    __shared__ float ringb[RING][RPB][BSZ];  // alpha history (block-local rows)
    __shared__ float rscr[6][8];
    __shared__ float rscr2[6];
    __shared__ float SD[8];                  // 0..2 = S_r, 3..5 = D_r, 6 = den
    __shared__ int   stopsh;

    const int  i   = tid;
    const bool act = (i < BM1);

    int   bI[RPB];
    float a[RPB], p[RPB], kb[RPB];
    #pragma unroll
    for (int r = 0; r < RPB; ++r) {
        const int b = g * RPB + r;
        const int I = i + (i >= b);
        bI[r] = I;
        if (act) {
            float v = alpha_init[(size_t)b * BM1 + i];
            v = fminf(fmaxf(v, 0.f), 1.f);
            a[r] = v; p[r] = v;
            kb[r] = Km[(size_t)b * NZTOT + I];
        } else { a[r] = 0.f; p[r] = 0.f; kb[r] = 0.f; }
    }

    const int h   = tid / 192;       // J-half group (3 waves each)
    const int u   = tid - h * 192;   // 0..191 -> outputs 2u, 2u+1
    const int Jlo = h * 192;

    int verified = 0;
    int stopT = -1;

    for (int t = 0; t < NITER; ++t) {
        // ---- non-blocking stop scan (tid 0); spins only if > RING behind ----
        if (tid == 0) {
            int st = -1;
            while (st < 0 && verified < t) {
                const bool need = (verified <= t - RING);
                int av = __hip_atomic_load(&arr[verified], __ATOMIC_ACQUIRE, __HIP_MEMORY_SCOPE_AGENT);
                if (av < NBLK) {
                    if (!need) break;
                    __builtin_amdgcn_s_sleep(1);
                    continue;
                }
                const float nn = __hip_atomic_load(&num[verified], __ATOMIC_RELAXED, __HIP_MEMORY_SCOPE_AGENT);
                const float dd = __hip_atomic_load(&den[verified], __ATOMIC_RELAXED, __HIP_MEMORY_SCOPE_AGENT);
                const float rel = sqrtf(nn) / (sqrtf(dd) + 1e-8f);
                if (rel < 0.01f) st = verified;
                else verified++;
            }
            stopsh = st;
        }

        // ---- phase 1: z build + S, D, den partials ----
        const float beta = (float)t / ((float)t + 3.0f);
        float z[RPB];
        float vv[7];
        {
            float denp = 0.f;
            #pragma unroll
            for (int r = 0; r < RPB; ++r) {
                if (act) {
                    const float zr = a[r] + beta * (a[r] - p[r]);
                    z[r] = zr;
                    zpack[bI[r]][r] = zr;
                    vv[r]     = zr;
                    vv[3 + r] = kb[r] * zr;
                    denp += a[r] * a[r];
                } else {
                    z[r] = 0.f;
                    zpack[g * RPB + r][r] = 0.f;   // diagonal hole
                    vv[r] = 0.f; vv[3 + r] = 0.f;
                }
            }
            vv[6] = denp;
        }
        #pragma unroll
        for (int k = 0; k < 7; ++k) {
            float x = vv[k];
            x += __shfl_down(x, 32, 64); x += __shfl_down(x, 16, 64);
            x += __shfl_down(x,  8, 64); x += __shfl_down(x,  4, 64);
            x += __shfl_down(x,  2, 64); x += __shfl_down(x,  1, 64);
            if (lane == 0) rscr[wv][k] = x;
        }
        __syncthreads();   // B1
        if (stopsh >= 0) { stopT = stopsh; break; }
        if (tid < 7) {
            float s = 0.f;
            for (int w = 0; w < 6; ++w) s += rscr[w][tid];
            SD[tid] = s;
        }

        // ---- phase 2: half-matvec, float2 K rows (symmetry), LDS z broadcast ----
        float a00 = 0.f, a01 = 0.f, a10 = 0.f, a11 = 0.f, a20 = 0.f, a21 = 0.f;
        {
            const float2* __restrict__ K2 = reinterpret_cast<const float2*>(Km);
            #pragma unroll 8
            for (int J = Jlo; J < Jlo + 192; ++J) {
                const float2 kv = K2[(size_t)J * 384 + u];
                const float4 zp = *reinterpret_cast<const float4*>(&zpack[J][0]);
                a00 = fmaf(kv.x, zp.x, a00); a01 = fmaf(kv.y, zp.x, a01);
                a10 = fmaf(kv.x, zp.y, a10); a11 = fmaf(kv.y, zp.y, a11);
                a20 = fmaf(kv.x, zp.z, a20); a21 = fmaf(kv.y, zp.z, a21);
            }
        }
        *reinterpret_cast<float2*>(&wpart[h][0][2*u]) = make_float2(a00, a01);
        *reinterpret_cast<float2*>(&wpart[h][1][2*u]) = make_float2(a10, a11);
        *reinterpret_cast<float2*>(&wpart[h][2][2*u]) = make_float2(a20, a21);
        __syncthreads();   // B2

        // ---- phase 3: grad, clipped step, num partial, ring write ----
        float nump = 0.f;
        #pragma unroll
        for (int r = 0; r < RPB; ++r) {
            if (act) {
                const int I = bI[r];
                const float w = wpart[0][r][I] + wpart[1][r][I];
                const float grad = SD[r] * (1.f - kb[r]) + 0.1f * z[r] + w - SD[3 + r] - 2.0f;
                float an = z[r] - 0.001f * grad;
                an = fminf(fmaxf(an, 0.f), 1.f);
                ringb[t & (RING - 1)][r][i] = an;
                const float d = an - a[r];
                nump += d * d;
                p[r] = a[r]; a[r] = an;
            }
        }
        {
            float x = nump;
            x += __shfl_down(x, 32, 64); x += __shfl_down(x, 16, 64);
            x += __shfl_down(x,  8, 64); x += __shfl_down(x,  4, 64);
            x += __shfl_down(x,  2, 64); x += __shfl_down(x,  1, 64);
            if (lane == 0) rscr2[wv] = x;
        }
        __syncthreads();   // B3
        if (tid == 0) {
            float nb = 0.f;
            for (int w = 0; w < 6; ++w) nb += rscr2[w];
            __hip_atomic_fetch_add(&num[t], nb, __ATOMIC_RELAXED, __HIP_MEMORY_SCOPE_AGENT);
            __hip_atomic_fetch_add(&den[t], SD[6], __ATOMIC_RELAXED, __HIP_MEMORY_SCOPE_AGENT);
            __hip_atomic_fetch_add(&arr[t], 1, __ATOMIC_RELEASE, __HIP_MEMORY_SCOPE_AGENT);
        }
    }

    // ---- finalize: write final alpha rows ----
    #pragma unroll
    for (int r = 0; r < RPB; ++r) {
        const int b = g * RPB + r;
        if (act) {
            const float av = (stopT >= 0) ? ringb[stopT & (RING - 1)][r][i] : a[r];
            afin[(size_t)b * BM1 + i] = av;
        }
    }
}

__global__ void __launch_bounds__(TPB)
loss_kernel(const float* __restrict__ Km, const float* __restrict__ afin,
            double* lossAcc) {
    const int b    = blockIdx.x;     // 0..383
    const int tid  = threadIdx.x;
    const int lane = tid & 63;
    const int wv   = tid >> 6;
    __shared__ double dscr[6][2];
    double np = 0.0, pp = 0.0;
    if (tid < BM1) {
        const float ay = afin[(size_t)b * BM1 + tid];
        const int   I  = tid + (tid >= b);
        np = (double)ay * (double)Km[(size_t)I * NZTOT + BSZ + b];
        pp = (double)ay * (double)Km[(size_t)b * NZTOT + BSZ + b];
    }
    for (int o = 32; o; o >>= 1) { np += __shfl_down(np, o, 64); pp += __shfl_down(pp, o, 64); }
    if (lane == 0) { dscr[wv][0] = np; dscr[wv][1] = pp; }
    __syncthreads();
    if (tid == 0) {
        double nb = 0.0, pb = 0.0;
        for (int w = 0; w < 6; ++w) { nb += dscr[w][0]; pb += dscr[w][1]; }
        __hip_atomic_fetch_add(&lossAcc[0], nb, __ATOMIC_RELAXED, __HIP_MEMORY_SCOPE_AGENT);
        __hip_atomic_fetch_add(&lossAcc[1], pb, __ATOMIC_RELAXED, __HIP_MEMORY_SCOPE_AGENT);
    }
}

__global__ void fin_kernel(const double* lossAcc, float* out) {
    out[0] = expf((float)(lossAcc[0] / 384.0 - lossAcc[1] / 384.0));
}

extern "C" void kernel_launch(void* const* d_in, const int* in_sizes, int n_in,
                              void* d_out, int out_size, void* d_ws, size_t ws_size,
                              hipStream_t stream) {
    const float* xis        = (const float*)d_in[0];
    const float* xjs        = (const float*)d_in[1];
    const float* alpha_init = (const float*)d_in[2];
    float* ws   = (float*)d_ws;
    float* Z    = ws + OFF_Z;
    float* nrm2 = ws + OFF_NRM;
    float* Km   = ws + OFF_K;
    float* afin = ws + OFF_A;
    float* num  = ws + OFF_NUM;
    float* den  = ws + OFF_DEN;
    int*   arr  = (int*)(ws + OFF_ARR);
    double* lossAcc = (double*)(ws + OFF_LOSS);
    float* out  = (float*)d_out;

    hipLaunchKernelGGL(init_kernel, dim3(1), dim3(128), 0, stream, num, den, arr, lossAcc);
    hipLaunchKernelGGL(norm_kernel, dim3(NZTOT), dim3(64), 0, stream, xis, xjs, Z, nrm2);
    hipLaunchKernelGGL(k_kernel, dim3(BSZ, 3), dim3(256), 0, stream, Z, nrm2, Km);
    hipLaunchKernelGGL(pgd_kernel, dim3(NBLK), dim3(TPB), 0, stream,
                       Km, alpha_init, afin, num, den, arr);
    hipLaunchKernelGGL(loss_kernel, dim3(BSZ), dim3(TPB), 0, stream, Km, afin, lossAcc);
    hipLaunchKernelGGL(fin_kernel, dim3(1), dim3(1), 0, stream, lossAcc, out);
}

// Round 3
// 1278.252 us; speedup vs baseline: 2.0918x; 2.0918x over previous
//
#include <hip/hip_runtime.h>
#include <math.h>

#define BSZ   384
#define BM1   383
#define DIM   256
#define NZTOT 768
#define NBLK  128
#define RPB   3
#define TPB   384
#define NITER 100
#define RING  4

// ---- ws layout (float offsets) ----
#define OFF_Z    0          // 768*256 = 196608
#define OFF_NRM  196608     // 768
#define OFF_K    197376     // 384*768 = 294912
#define OFF_A    492288     // 384*383 = 147072 (final alpha)
#define OFF_NUM  639360     // NITER floats (pad 128)
#define OFF_DEN  639488     // NITER floats (pad 128)
#define OFF_ARR  639616     // NITER ints  (pad 128)
#define OFF_LOSS 639744     // 2 doubles (byte 2558976, 8B aligned)
// total ~2.56 MB

__device__ __forceinline__ void fma4(float4& a, const float4 k, const float s) {
    a.x = fmaf(k.x, s, a.x); a.y = fmaf(k.y, s, a.y);
    a.z = fmaf(k.z, s, a.z); a.w = fmaf(k.w, s, a.w);
}

__global__ void init_kernel(float* num, float* den, int* arr, double* lossAcc) {
    int t = threadIdx.x;
    if (t < NITER) { num[t] = 0.f; den[t] = 0.f; arr[t] = 0; }
    if (t < 2) lossAcc[t] = 0.0;
}

__global__ void __launch_bounds__(64)
norm_kernel(const float* __restrict__ xis, const float* __restrict__ xjs,
            float* __restrict__ Z, float* __restrict__ nrm2) {
    const int row  = blockIdx.x;     // 0..767
    const int lane = threadIdx.x;    // 0..63
    const float* src = (row < BSZ) ? (xis + (size_t)row * DIM)
                                   : (xjs + (size_t)(row - BSZ) * DIM);
    float4 x = reinterpret_cast<const float4*>(src)[lane];
    float s = x.x*x.x + x.y*x.y + x.z*x.z + x.w*x.w;
    for (int m = 32; m; m >>= 1) s += __shfl_xor(s, m, 64);
    float nrm = sqrtf(s);
    float4 z;
    z.x = x.x / nrm; z.y = x.y / nrm; z.z = x.z / nrm; z.w = x.w / nrm;
    reinterpret_cast<float4*>(Z + (size_t)row * DIM)[lane] = z;
    float s2 = z.x*z.x + z.y*z.y + z.z*z.z + z.w*z.w;
    for (int m = 32; m; m >>= 1) s2 += __shfl_xor(s2, m, 64);
    if (lane == 0) nrm2[row] = s2;
}

__global__ void __launch_bounds__(256)
k_kernel(const float* __restrict__ Z, const float* __restrict__ nrm2,
         float* __restrict__ Km) {
    const int i = blockIdx.x;                        // 0..383
    const int j = blockIdx.y * 256 + threadIdx.x;    // 0..767
    __shared__ float zi[DIM];
    zi[threadIdx.x] = Z[(size_t)i * DIM + threadIdx.x];
    __syncthreads();
    const float4* zr = reinterpret_cast<const float4*>(Z + (size_t)j * DIM);
    float acc = 0.f;
    #pragma unroll 8
    for (int k = 0; k < DIM/4; ++k) {
        float4 v = zr[k];
        acc = fmaf(zi[4*k+0], v.x, acc);
        acc = fmaf(zi[4*k+1], v.y, acc);
        acc = fmaf(zi[4*k+2], v.z, acc);
        acc = fmaf(zi[4*k+3], v.w, acc);
    }
    float sq = nrm2[i] + nrm2[j] - 2.f * acc;
    sq = fmaxf(sq, 0.f);
    Km[(size_t)i * NZTOT + j] = expf(-0.1f * sq);
}

// ---- phase-2 macros: load one 4-J group, compute one 4-J group ----
#define LDG(Jg, K0,K1,K2,K3, Z0,Z1,Z2) do { const int _J = (Jg);            \
    K0 = KK4[(size_t)(_J+0)*192 + u];  K1 = KK4[(size_t)(_J+1)*192 + u];    \
    K2 = KK4[(size_t)(_J+2)*192 + u];  K3 = KK4[(size_t)(_J+3)*192 + u];    \
    Z0 = *reinterpret_cast<const float4*>(&zrow[0][_J]);                    \
    Z1 = *reinterpret_cast<const float4*>(&zrow[1][_J]);                    \
    Z2 = *reinterpret_cast<const float4*>(&zrow[2][_J]); } while (0)

#define CMPG(K0,K1,K2,K3, Z0,Z1,Z2) do {                                    \
    fma4(acc0, K0, Z0.x); fma4(acc0, K1, Z0.y);                             \
    fma4(acc0, K2, Z0.z); fma4(acc0, K3, Z0.w);                             \
    fma4(acc1, K0, Z1.x); fma4(acc1, K1, Z1.y);                             \
    fma4(acc1, K2, Z1.z); fma4(acc1, K3, Z1.w);                             \
    fma4(acc2, K0, Z2.x); fma4(acc2, K1, Z2.y);                             \
    fma4(acc2, K2, Z2.z); fma4(acc2, K3, Z2.w); } while (0)

__global__ void __launch_bounds__(TPB, 1)
pgd_kernel(const float* __restrict__ Km, const float* __restrict__ alpha_init,
           float* __restrict__ afin, float* num, float* den, int* arr) {
    const int g    = blockIdx.x;     // 0..127
    const int tid  = threadIdx.x;    // 0..383
    const int lane = tid & 63;
    const int wv   = tid >> 6;       // 0..5

    __shared__ float zrow[RPB][388];         // z rows (row-major, conflict-free writes)
    __shared__ float wpart[4][RPB][BSZ];     // per-quarter partial matvec
    __shared__ float ringb[RING][RPB][BSZ];  // alpha history (block-local rows)
    __shared__ float rscr[6][8];
    __shared__ float rscr2[6];
    __shared__ float SD[8];                  // 0..2 = S_r, 3..5 = D_r, 6 = den
    __shared__ int   stopsh;

    const int  i   = tid;
    const bool act = (i < BM1);

    int   bI[RPB];
    float a[RPB], p[RPB], kb[RPB];
    #pragma unroll
    for (int r = 0; r < RPB; ++r) {
        const int b = g * RPB + r;
        const int I = i + (i >= b);
        bI[r] = I;
        if (act) {
            float v = alpha_init[(size_t)b * BM1 + i];
            v = fminf(fmaxf(v, 0.f), 1.f);
            a[r] = v; p[r] = v;
            kb[r] = Km[(size_t)b * NZTOT + I];
        } else { a[r] = 0.f; p[r] = 0.f; kb[r] = 0.f; }
    }

    const int q  = tid / 96;         // J-quarter group
    const int u  = tid - q * 96;     // 0..95 -> output columns 4u..4u+3
    const int J0 = q * 96;
    const float4* __restrict__ KK4 = reinterpret_cast<const float4*>(Km);

    int verified = 0;
    int stopT = -1;

    for (int t = 0; t < NITER; ++t) {
        // ---- non-blocking stop scan (tid 0); spins only if > RING behind ----
        if (tid == 0) {
            int st = -1;
            while (st < 0 && verified < t) {
                const bool need = (verified <= t - RING);
                int av = __hip_atomic_load(&arr[verified], __ATOMIC_ACQUIRE, __HIP_MEMORY_SCOPE_AGENT);
                if (av < NBLK) {
                    if (!need) break;
                    __builtin_amdgcn_s_sleep(1);
                    continue;
                }
                const float nn = __hip_atomic_load(&num[verified], __ATOMIC_RELAXED, __HIP_MEMORY_SCOPE_AGENT);
                const float dd = __hip_atomic_load(&den[verified], __ATOMIC_RELAXED, __HIP_MEMORY_SCOPE_AGENT);
                const float rel = sqrtf(nn) / (sqrtf(dd) + 1e-8f);
                if (rel < 0.01f) st = verified;
                else verified++;
            }
            stopsh = st;
        }

        // ---- phase 1: z build + S, D, den partials ----
        const float beta = (float)t / ((float)t + 3.0f);
        float z[RPB];
        float vv[7];
        {
            float denp = 0.f;
            #pragma unroll
            for (int r = 0; r < RPB; ++r) {
                if (act) {
                    const float zr = a[r] + beta * (a[r] - p[r]);
                    z[r] = zr;
                    zrow[r][bI[r]] = zr;
                    vv[r]     = zr;
                    vv[3 + r] = kb[r] * zr;
                    denp += a[r] * a[r];
                } else {
                    z[r] = 0.f;
                    zrow[r][g * RPB + r] = 0.f;   // diagonal hole
                    vv[r] = 0.f; vv[3 + r] = 0.f;
                }
            }
            vv[6] = denp;
        }
        #pragma unroll
        for (int k = 0; k < 7; ++k) {
            float x = vv[k];
            x += __shfl_down(x, 32, 64); x += __shfl_down(x, 16, 64);
            x += __shfl_down(x,  8, 64); x += __shfl_down(x,  4, 64);
            x += __shfl_down(x,  2, 64); x += __shfl_down(x,  1, 64);
            if (lane == 0) rscr[wv][k] = x;
        }
        __syncthreads();   // B1
        if (stopsh >= 0) { stopT = stopsh; break; }
        if (tid < 7) {
            float s = 0.f;
            for (int w = 0; w < 6; ++w) s += rscr[w][tid];
            SD[tid] = s;
        }

        // ---- phase 2: quarter-matvec, depth-3 software pipeline ----
        float4 acc0 = make_float4(0.f,0.f,0.f,0.f);
        float4 acc1 = make_float4(0.f,0.f,0.f,0.f);
        float4 acc2 = make_float4(0.f,0.f,0.f,0.f);
        {
            float4 ka0,ka1,ka2,ka3, za0,za1,za2;
            float4 kb0,kb1,kb2,kb3, zb0,zb1,zb2;
            float4 kc0,kc1,kc2,kc3, zc0,zc1,zc2;
            LDG(J0 + 0, ka0,ka1,ka2,ka3, za0,za1,za2);
            LDG(J0 + 4, kb0,kb1,kb2,kb3, zb0,zb1,zb2);
            int J = J0;
            #pragma unroll 1
            for (int it = 0; it < 7; ++it) {
                LDG(J + 8,  kc0,kc1,kc2,kc3, zc0,zc1,zc2);
                CMPG(ka0,ka1,ka2,ka3, za0,za1,za2);
                LDG(J + 12, ka0,ka1,ka2,ka3, za0,za1,za2);
                CMPG(kb0,kb1,kb2,kb3, zb0,zb1,zb2);
                LDG(J + 16, kb0,kb1,kb2,kb3, zb0,zb1,zb2);
                CMPG(kc0,kc1,kc2,kc3, zc0,zc1,zc2);
                J += 12;
            }
            // epilogue: J = J0+84; groups 84..87(A), 88..91(B), 92..95(C)
            LDG(J + 8, kc0,kc1,kc2,kc3, zc0,zc1,zc2);
            CMPG(ka0,ka1,ka2,ka3, za0,za1,za2);
            CMPG(kb0,kb1,kb2,kb3, zb0,zb1,zb2);
            CMPG(kc0,kc1,kc2,kc3, zc0,zc1,zc2);
        }
        *reinterpret_cast<float4*>(&wpart[q][0][4*u]) = acc0;
        *reinterpret_cast<float4*>(&wpart[q][1][4*u]) = acc1;
        *reinterpret_cast<float4*>(&wpart[q][2][4*u]) = acc2;
        __syncthreads();   // B2

        // ---- phase 3: grad, clipped step, num partial, ring write ----
        float nump = 0.f;
        #pragma unroll
        for (int r = 0; r < RPB; ++r) {
            if (act) {
                const int I = bI[r];
                const float w = (wpart[0][r][I] + wpart[1][r][I])
                              + (wpart[2][r][I] + wpart[3][r][I]);
                const float grad = SD[r] * (1.f - kb[r]) + 0.1f * z[r] + w - SD[3 + r] - 2.0f;
                float an = z[r] - 0.001f * grad;
                an = fminf(fmaxf(an, 0.f), 1.f);
                ringb[t & (RING - 1)][r][i] = an;
                const float d = an - a[r];
                nump += d * d;
                p[r] = a[r]; a[r] = an;
            }
        }
        {
            float x = nump;
            x += __shfl_down(x, 32, 64); x += __shfl_down(x, 16, 64);
            x += __shfl_down(x,  8, 64); x += __shfl_down(x,  4, 64);
            x += __shfl_down(x,  2, 64); x += __shfl_down(x,  1, 64);
            if (lane == 0) rscr2[wv] = x;
        }
        __syncthreads();   // B3
        if (tid == 0) {
            float nb = 0.f;
            for (int w = 0; w < 6; ++w) nb += rscr2[w];
            __hip_atomic_fetch_add(&num[t], nb, __ATOMIC_RELAXED, __HIP_MEMORY_SCOPE_AGENT);
            __hip_atomic_fetch_add(&den[t], SD[6], __ATOMIC_RELAXED, __HIP_MEMORY_SCOPE_AGENT);
            __hip_atomic_fetch_add(&arr[t], 1, __ATOMIC_RELEASE, __HIP_MEMORY_SCOPE_AGENT);
        }
    }

    // ---- finalize: write final alpha rows ----
    #pragma unroll
    for (int r = 0; r < RPB; ++r) {
        const int b = g * RPB + r;
        if (act) {
            const float av = (stopT >= 0) ? ringb[stopT & (RING - 1)][r][i] : a[r];
            afin[(size_t)b * BM1 + i] = av;
        }
    }
}

__global__ void __launch_bounds__(TPB)
loss_kernel(const float* __restrict__ Km, const float* __restrict__ afin,
            double* lossAcc) {
    const int b    = blockIdx.x;     // 0..383
    const int tid  = threadIdx.x;
    const int lane = tid & 63;
    const int wv   = tid >> 6;
    __shared__ double dscr[6][2];
    double np = 0.0, pp = 0.0;
    if (tid < BM1) {
        const float ay = afin[(size_t)b * BM1 + tid];
        const int   I  = tid + (tid >= b);
        np = (double)ay * (double)Km[(size_t)I * NZTOT + BSZ + b];
        pp = (double)ay * (double)Km[(size_t)b * NZTOT + BSZ + b];
    }
    for (int o = 32; o; o >>= 1) { np += __shfl_down(np, o, 64); pp += __shfl_down(pp, o, 64); }
    if (lane == 0) { dscr[wv][0] = np; dscr[wv][1] = pp; }
    __syncthreads();
    if (tid == 0) {
        double nb = 0.0, pb = 0.0;
        for (int w = 0; w < 6; ++w) { nb += dscr[w][0]; pb += dscr[w][1]; }
        __hip_atomic_fetch_add(&lossAcc[0], nb, __ATOMIC_RELAXED, __HIP_MEMORY_SCOPE_AGENT);
        __hip_atomic_fetch_add(&lossAcc[1], pb, __ATOMIC_RELAXED, __HIP_MEMORY_SCOPE_AGENT);
    }
}

__global__ void fin_kernel(const double* lossAcc, float* out) {
    out[0] = expf((float)(lossAcc[0] / 384.0 - lossAcc[1] / 384.0));
}

extern "C" void kernel_launch(void* const* d_in, const int* in_sizes, int n_in,
                              void* d_out, int out_size, void* d_ws, size_t ws_size,
                              hipStream_t stream) {
    const float* xis        = (const float*)d_in[0];
    const float* xjs        = (const float*)d_in[1];
    const float* alpha_init = (const float*)d_in[2];
    float* ws   = (float*)d_ws;
    float* Z    = ws + OFF_Z;
    float* nrm2 = ws + OFF_NRM;
    float* Km   = ws + OFF_K;
    float* afin = ws + OFF_A;
    float* num  = ws + OFF_NUM;
    float* den  = ws + OFF_DEN;
    int*   arr  = (int*)(ws + OFF_ARR);
    double* lossAcc = (double*)(ws + OFF_LOSS);
    float* out  = (float*)d_out;

    hipLaunchKernelGGL(init_kernel, dim3(1), dim3(128), 0, stream, num, den, arr, lossAcc);
    hipLaunchKernelGGL(norm_kernel, dim3(NZTOT), dim3(64), 0, stream, xis, xjs, Z, nrm2);
    hipLaunchKernelGGL(k_kernel, dim3(BSZ, 3), dim3(256), 0, stream, Z, nrm2, Km);
    hipLaunchKernelGGL(pgd_kernel, dim3(NBLK), dim3(TPB), 0, stream,
                       Km, alpha_init, afin, num, den, arr);
    hipLaunchKernelGGL(loss_kernel, dim3(BSZ), dim3(TPB), 0, stream, Km, afin, lossAcc);
    hipLaunchKernelGGL(fin_kernel, dim3(1), dim3(1), 0, stream, lossAcc, out);
}